// Round 1
// baseline (136.552 us; speedup 1.0000x reference)
//
#include <hip/hip_runtime.h>

// SIM hard search: per-column stream compaction of first K topic-matching
// values. L=2048, B=4096, K=256 nominal; derived at launch from sizes.
//
// Layout: block = 256 threads = 16 columns (fast) x 16 row-chunks.
// Each thread scans a 128-row chunk of one column, builds a 128-bit match
// bitmask (so user_seq is only read at matched positions), then an LDS
// exclusive scan over chunks gives each chunk its output base rank.

#define NCH 16   // row-chunks per column (all within one block)
#define CPB 16   // columns per block

__global__ __launch_bounds__(256) void simhs_kernel(
    const float* __restrict__ user_seq,
    const int*   __restrict__ topics,
    const int*   __restrict__ tgt_topic,
    float*       __restrict__ out,
    int L, int B, int K, int chunkRows)
{
    __shared__ int s_cnt[NCH][CPB];

    const int t   = threadIdx.x;
    const int ci  = t & (CPB - 1);   // column within block (fast dim -> coalesced)
    const int ch  = t >> 4;          // chunk index 0..15
    const int col = blockIdx.x * CPB + ci;
    const bool colOK = (col < B);

    // ---- Phase 0: zero-init this block's output columns ----
    if (colOK) {
        for (int k = ch; k < K; k += NCH)
            out[(size_t)k * B + col] = 0.0f;
    }

    const int tt = colOK ? tgt_topic[col] : -1;

    const int r0 = ch * chunkRows;
    const int r1 = (r0 + chunkRows < L) ? (r0 + chunkRows) : L;

    // ---- Phase 1: scan rows, build 128-bit match mask ----
    unsigned long long m0 = 0ull, m1 = 0ull;   // rows [r0, r0+64), [r0+64, r0+128)
    if (colOK) {
        const int* tp = topics + col;
        #pragma unroll 8
        for (int r = r0; r < r1; ++r) {
            int v = tp[(size_t)r * B];
            int lr = r - r0;
            unsigned long long bit = (v == tt) ? 1ull : 0ull;
            if (lr < 64) m0 |= bit << lr;
            else         m1 |= bit << (lr - 64);
        }
    }
    int cnt = __popcll(m0) + __popcll(m1);
    s_cnt[ch][ci] = cnt;
    __syncthreads();

    // ---- Phase 2: exclusive scan over chunks, per column ----
    if (ch == 0) {
        int acc = 0;
        #pragma unroll
        for (int c = 0; c < NCH; ++c) {
            int v = s_cnt[c][ci];
            s_cnt[c][ci] = acc;
            acc += v;
        }
    }
    __syncthreads();

    // ---- Phase 3: gather matched values, scatter to output ranks ----
    if (colOK) {
        int base = s_cnt[ch][ci];
        const float* us = user_seq + col;
        unsigned long long m = m0;
        int off = 0;
        #pragma unroll 1
        for (int half = 0; half < 2; ++half) {
            while (m) {
                if (base >= K) break;
                int lr = __ffsll((unsigned long long)m) - 1;
                m &= m - 1;
                int r = r0 + off + lr;
                out[(size_t)base * B + col] = us[(size_t)r * B];
                ++base;
            }
            m = m1;
            off = 64;
        }
    }
}

extern "C" void kernel_launch(void* const* d_in, const int* in_sizes, int n_in,
                              void* d_out, int out_size, void* d_ws, size_t ws_size,
                              hipStream_t stream) {
    const float* user_seq = (const float*)d_in[0];
    // d_in[1] = target_item (unused by the reference computation)
    const int* topics = (const int*)d_in[2];
    const int* tgt    = (const int*)d_in[3];
    // d_in[4] = top_k scalar on device; recover K from out_size instead.

    const int B = in_sizes[1];            // 4096
    const int L = in_sizes[0] / B;        // 2048
    const int K = out_size / B;           // 256
    const int chunkRows = (L + NCH - 1) / NCH;   // 128 (must be <= 128 for bitmask)

    const int grid = (B + CPB - 1) / CPB; // 256 blocks

    simhs_kernel<<<grid, 256, 0, stream>>>(
        user_seq, topics, tgt, (float*)d_out, L, B, K, chunkRows);
}

// Round 2
// 103.710 us; speedup vs baseline: 1.3167x; 1.3167x over previous
//
#include <hip/hip_runtime.h>

// SIM hard search: per-column stream compaction of first K topic-matching
// values. L=2048, B=4096, K=256 nominal; derived at launch from sizes.
//
// Round 2: occupancy fix. Block = 1024 threads = 16 columns (fast dim,
// coalesced) x 64 row-chunks of 32 rows each. Each thread scans 32 rows of
// one column into a 64-bit match bitmask, an LDS Hillis-Steele scan over the
// 64 chunks gives each chunk its output base rank, then matched values are
// gathered and scattered. 4x the threads of round 1 (262144 total,
// 16 waves/CU) to hide HBM latency.

#define NCH 64   // row-chunks per column (all within one block)
#define CPB 16   // columns per block

__global__ __launch_bounds__(1024) void simhs_kernel(
    const float* __restrict__ user_seq,
    const int*   __restrict__ topics,
    const int*   __restrict__ tgt_topic,
    float*       __restrict__ out,
    int L, int B, int K, int chunkRows)
{
    __shared__ int s_cnt[NCH][CPB];

    const int t   = threadIdx.x;
    const int ci  = t & (CPB - 1);   // column within block (fast dim -> coalesced)
    const int ch  = t >> 4;          // chunk index 0..63
    const int col = blockIdx.x * CPB + ci;
    const bool colOK = (col < B);

    // ---- Phase 0: zero-init this block's output columns ----
    if (colOK) {
        for (int k = ch; k < K; k += NCH)
            out[(size_t)k * B + col] = 0.0f;
    }

    const int tt = colOK ? tgt_topic[col] : -1;

    const int r0 = ch * chunkRows;
    const int r1 = (r0 + chunkRows < L) ? (r0 + chunkRows) : L;

    // ---- Phase 1: scan rows, build 64-bit match mask (chunkRows <= 64) ----
    unsigned long long m0 = 0ull;
    if (colOK) {
        const int* tp = topics + col;
        #pragma unroll 16
        for (int r = r0; r < r1; ++r) {
            int v = tp[(size_t)r * B];
            unsigned long long bit = (v == tt) ? 1ull : 0ull;
            m0 |= bit << (r - r0);
        }
    }
    int cnt = __popcll(m0);
    s_cnt[ch][ci] = cnt;
    __syncthreads();

    // ---- Phase 2: Hillis-Steele inclusive scan over chunks, per column ----
    #pragma unroll
    for (int d = 1; d < NCH; d <<= 1) {
        int v   = s_cnt[ch][ci];
        int add = (ch >= d) ? s_cnt[ch - d][ci] : 0;
        __syncthreads();
        s_cnt[ch][ci] = v + add;
        __syncthreads();
    }

    // ---- Phase 3: gather matched values, scatter to output ranks ----
    if (colOK) {
        int base = s_cnt[ch][ci] - cnt;   // exclusive rank base for this chunk
        const float* us = user_seq + col;
        unsigned long long m = m0;
        while (m) {
            if (base >= K) break;
            int lr = __ffsll(m) - 1;
            m &= m - 1;
            int r = r0 + lr;
            out[(size_t)base * B + col] = us[(size_t)r * B];
            ++base;
        }
    }
}

extern "C" void kernel_launch(void* const* d_in, const int* in_sizes, int n_in,
                              void* d_out, int out_size, void* d_ws, size_t ws_size,
                              hipStream_t stream) {
    const float* user_seq = (const float*)d_in[0];
    // d_in[1] = target_item (unused by the reference computation)
    const int* topics = (const int*)d_in[2];
    const int* tgt    = (const int*)d_in[3];
    // d_in[4] = top_k scalar on device; recover K from out_size instead.

    const int B = in_sizes[1];            // 4096
    const int L = in_sizes[0] / B;        // 2048
    const int K = out_size / B;           // 256
    const int chunkRows = (L + NCH - 1) / NCH;   // 32 (must be <= 64 for bitmask)

    const int grid = (B + CPB - 1) / CPB; // 256 blocks

    simhs_kernel<<<grid, 1024, 0, stream>>>(
        user_seq, topics, tgt, (float*)d_out, L, B, K, chunkRows);
}